// Round 1
// baseline (250.229 us; speedup 1.0000x reference)
//
#include <hip/hip_runtime.h>
#include <hip/hip_bf16.h>

// ---------------- problem constants ----------------
#define B_N   8
#define S_N   4096
#define D_N   256          // DQK == DV
#define QBLK  64           // q rows per block (16 per wave, 4 waves)
#define KVBLK 64
#define SCALE 0.0625f      // 1/sqrt(256)

typedef __attribute__((ext_vector_type(8))) short  bf16x8;
typedef __attribute__((ext_vector_type(4))) float  f32x4;

// ---------------- async global->LDS (16B/lane, wave-uniform LDS base) -------
__device__ __forceinline__ void async16(const char* g, char* l) {
  __builtin_amdgcn_global_load_lds(
      (const __attribute__((address_space(1))) void*)g,
      (__attribute__((address_space(3))) void*)l, 16, 0, 0);
}

// ---------------- prepass: NCHW -> (B,S,D) bf16 with pos add ----------------
// src[b][c][s] fp32, pos[s][c] fp32  ->  dst[b][s][c] bf16
__global__ void prep_qk(const float* __restrict__ src, const float* __restrict__ pos,
                        __hip_bfloat16* __restrict__ dst) {
  __shared__ float tile[64][65];
  const int b  = blockIdx.z;
  const int s0 = blockIdx.x * 64;
  const int c0 = blockIdx.y * 64;
  const int t  = threadIdx.x;
  const int x  = t & 63;     // inner (coalesced) index
  const int y4 = t >> 6;     // 0..3
  const float* sp = src + ((size_t)b * D_N + c0) * S_N + s0;
#pragma unroll
  for (int i = 0; i < 16; ++i) {
    int c = y4 + i * 4;
    tile[c][x] = sp[(size_t)c * S_N + x];        // read coalesced along s
  }
  __syncthreads();
  __hip_bfloat16* dp = dst + ((size_t)b * S_N + s0) * D_N + c0;
  const float* pp = pos + (size_t)s0 * D_N + c0;
#pragma unroll
  for (int i = 0; i < 16; ++i) {
    int s = y4 + i * 4;
    float v = tile[x][s] + pp[(size_t)s * D_N + x];   // pos read coalesced along c
    dp[(size_t)s * D_N + x] = __float2bfloat16(v);    // write coalesced along c
  }
}

// V: (B,D,S) fp32 -> (B,D,S) bf16 (pure cast; V^T layout is what PV's B-operand wants)
struct alignas(8) bf4 { __hip_bfloat16 a, b, c, d; };
__global__ void prep_v(const float* __restrict__ src, __hip_bfloat16* __restrict__ dst) {
  size_t i = (size_t)blockIdx.x * blockDim.x + threadIdx.x;   // float4 index
  float4 v = reinterpret_cast<const float4*>(src)[i];
  bf4 o { __float2bfloat16(v.x), __float2bfloat16(v.y),
          __float2bfloat16(v.z), __float2bfloat16(v.w) };
  *reinterpret_cast<bf4*>(dst + i * 4) = o;
}

// ---------------- flash attention ----------------
// LDS map: [0,32KB) K tile (64 keys x 512B, XOR-swizzled cols)
//          [32KB,64KB) Vt tile (256 d x 128B, XOR-swizzled cols)
//          [64KB, +9216) per-wave P buffers (16 rows x 144B)
// epilogue reuses [0, 65792) as O tile 64 x 257 f32
#define P_STRIDE 144
#define LDS_BYTES 74752

__global__ __launch_bounds__(256, 2) void attn_kernel(
    const __hip_bfloat16* __restrict__ Qb, const __hip_bfloat16* __restrict__ Kb,
    const __hip_bfloat16* __restrict__ Vtb, float* __restrict__ out) {
  __shared__ __align__(16) char lds[LDS_BYTES];

  const int tid  = threadIdx.x;
  const int wave = tid >> 6;
  const int lane = tid & 63;
  const int l15  = lane & 15;
  const int l4   = lane >> 4;

  // XCD-chunked swizzle: hardware blocks = k (mod 8) -> all of batch k on XCD k
  const int lin = blockIdx.x;                 // 0..511
  const int swz = (lin & 7) * 64 + (lin >> 3);
  const int b   = swz >> 6;
  const int q0blk = (swz & 63) * QBLK;
  const int q0    = q0blk + wave * 16;

  // Q fragments (A-layout: row = l15, k = l4*8 + j within each 32-chunk)
  bf16x8 qf[8];
  {
    const __hip_bfloat16* qp = Qb + ((size_t)b * S_N + q0 + l15) * D_N + l4 * 8;
#pragma unroll
    for (int kc = 0; kc < 8; ++kc)
      qf[kc] = *reinterpret_cast<const bf16x8*>(qp + kc * 32);
  }

  f32x4 o[16];
#pragma unroll
  for (int i = 0; i < 16; ++i) o[i] = f32x4{0.f, 0.f, 0.f, 0.f};
  float m_[4] = {-1e30f, -1e30f, -1e30f, -1e30f};
  float l_[4] = {0.f, 0.f, 0.f, 0.f};

  char* Klds = lds;
  char* Vlds = lds + 32768;
  char* Pw   = lds + 65536 + wave * (16 * P_STRIDE);

  const char* kgbase = reinterpret_cast<const char*>(Kb  + (size_t)b * S_N * D_N);
  const char* vgbase = reinterpret_cast<const char*>(Vtb + (size_t)b * D_N * S_N);

  for (int t = 0; t < S_N / KVBLK; ++t) {
    __syncthreads();   // previous tile fully consumed
    {
      // K tile: 64 rows x 512B; source pre-swizzled so linear LDS holds swizzled data
      const char* kt = kgbase + (size_t)t * KVBLK * (D_N * 2);
#pragma unroll
      for (int i = 0; i < 8; ++i) {
        int c    = wave * 8 + i;              // 32 wave-calls of 1KB
        int Tb   = c * 1024 + lane * 16;
        int row  = Tb >> 9;
        int colb = Tb & 511;
        async16(kt + row * 512 + (colb ^ ((row & 7) << 4)), Klds + c * 1024);
      }
      // Vt tile: 256 d-rows x 128B (global row stride S*2 = 8192B)
      const char* vt = vgbase + (size_t)t * KVBLK * 2;
#pragma unroll
      for (int i = 0; i < 8; ++i) {
        int c    = wave * 8 + i;
        int Tb   = c * 1024 + lane * 16;
        int d    = Tb >> 7;
        int colb = Tb & 127;
        async16(vt + (size_t)d * (S_N * 2) + (colb ^ ((d & 7) << 4)), Vlds + c * 1024);
      }
    }
    __syncthreads();   // staged data visible (vmcnt drained by barrier semantics)

    // ---- QK^T: 4 n-frags x 8 k-chunks ----
    float sv[4][4];
#pragma unroll
    for (int nf = 0; nf < 4; ++nf) {
      f32x4 sa = f32x4{0.f, 0.f, 0.f, 0.f};
      const int key  = nf * 16 + l15;
      const char* kr = Klds + key * 512;
      const int kswz = (key & 7) << 4;
#pragma unroll
      for (int kc = 0; kc < 8; ++kc) {
        bf16x8 kf = *reinterpret_cast<const bf16x8*>(kr + ((kc * 64 + l4 * 16) ^ kswz));
        sa = __builtin_amdgcn_mfma_f32_16x16x32_bf16(qf[kc], kf, sa, 0, 0, 0);
      }
#pragma unroll
      for (int r = 0; r < 4; ++r) sv[nf][r] = sa[r] * SCALE;
    }

    // ---- online softmax (rows live in reg r; 16-lane groups share a row) ----
    float alpha[4];
#pragma unroll
    for (int r = 0; r < 4; ++r) {
      float mx = fmaxf(fmaxf(sv[0][r], sv[1][r]), fmaxf(sv[2][r], sv[3][r]));
      mx = fmaxf(mx, __shfl_xor(mx, 1));
      mx = fmaxf(mx, __shfl_xor(mx, 2));
      mx = fmaxf(mx, __shfl_xor(mx, 4));
      mx = fmaxf(mx, __shfl_xor(mx, 8));
      float mn = fmaxf(m_[r], mx);
      alpha[r] = __expf(m_[r] - mn);
      m_[r] = mn;
      float rs = 0.f;
#pragma unroll
      for (int nf = 0; nf < 4; ++nf) { sv[nf][r] = __expf(sv[nf][r] - mn); rs += sv[nf][r]; }
      rs += __shfl_xor(rs, 1);
      rs += __shfl_xor(rs, 2);
      rs += __shfl_xor(rs, 4);
      rs += __shfl_xor(rs, 8);
      l_[r] = l_[r] * alpha[r] + rs;
    }
#pragma unroll
    for (int i = 0; i < 16; ++i) {
      o[i][0] *= alpha[0]; o[i][1] *= alpha[1];
      o[i][2] *= alpha[2]; o[i][3] *= alpha[3];
    }

    // ---- P (C-layout) -> bf16 -> per-wave LDS -> A-layout frags ----
#pragma unroll
    for (int r = 0; r < 4; ++r) {
      __hip_bfloat16* pr = reinterpret_cast<__hip_bfloat16*>(Pw + (l4 * 4 + r) * P_STRIDE);
#pragma unroll
      for (int nf = 0; nf < 4; ++nf)
        pr[nf * 16 + l15] = __float2bfloat16(sv[nf][r]);
    }
    bf16x8 pa0 = *reinterpret_cast<const bf16x8*>(Pw + l15 * P_STRIDE + l4 * 16);
    bf16x8 pa1 = *reinterpret_cast<const bf16x8*>(Pw + l15 * P_STRIDE + 64 + l4 * 16);

    // ---- PV: 16 d-frags x 2 k-chunks ----
#pragma unroll
    for (int df = 0; df < 16; ++df) {
      const int d    = df * 16 + l15;
      const char* vr = Vlds + d * 128;
      const int dswz = (d & 7) << 4;
      bf16x8 v0 = *reinterpret_cast<const bf16x8*>(vr + ((l4 * 16) ^ dswz));
      bf16x8 v1 = *reinterpret_cast<const bf16x8*>(vr + ((64 + l4 * 16) ^ dswz));
      o[df] = __builtin_amdgcn_mfma_f32_16x16x32_bf16(pa0, v0, o[df], 0, 0, 0);
      o[df] = __builtin_amdgcn_mfma_f32_16x16x32_bf16(pa1, v1, o[df], 0, 0, 0);
    }
  }

  // ---- epilogue: normalize, transpose via LDS, coalesced (B,D,S) store ----
  __syncthreads();
  float invl[4];
#pragma unroll
  for (int r = 0; r < 4; ++r) invl[r] = 1.0f / l_[r];
  float* Olds = reinterpret_cast<float*>(lds);   // 64 rows x 257 f32
#pragma unroll
  for (int df = 0; df < 16; ++df)
#pragma unroll
    for (int r = 0; r < 4; ++r)
      Olds[(wave * 16 + l4 * 4 + r) * 257 + df * 16 + l15] = o[df][r] * invl[r];
  __syncthreads();
  float* ob = out + (size_t)b * D_N * S_N + q0blk;
  const int x = tid & 63;
  const int y = tid >> 6;
#pragma unroll
  for (int i = 0; i < 64; ++i) {
    int d = y + i * 4;
    ob[(size_t)d * S_N + x] = Olds[x * 257 + d];
  }
}

// ---------------- launch ----------------
extern "C" void kernel_launch(void* const* d_in, const int* in_sizes, int n_in,
                              void* d_out, int out_size, void* d_ws, size_t ws_size,
                              hipStream_t stream) {
  const float* queries = (const float*)d_in[0];
  const float* keys    = (const float*)d_in[1];
  const float* values  = (const float*)d_in[2];
  const float* q_pos   = (const float*)d_in[3];
  const float* k_pos   = (const float*)d_in[4];
  float* out = (float*)d_out;

  const size_t per = (size_t)B_N * S_N * D_N;          // 8.39M elems
  __hip_bfloat16* Qb  = (__hip_bfloat16*)d_ws;
  __hip_bfloat16* Kb  = Qb + per;
  __hip_bfloat16* Vtb = Kb + per;                      // needs 3*per*2 = 50.3 MB of ws

  prep_qk<<<dim3(S_N / 64, D_N / 64, B_N), 256, 0, stream>>>(queries, q_pos, Qb);
  prep_qk<<<dim3(S_N / 64, D_N / 64, B_N), 256, 0, stream>>>(keys,    k_pos, Kb);
  prep_v <<<dim3((unsigned)(per / 4 / 256)), 256, 0, stream>>>(values, Vtb);
  attn_kernel<<<dim3((S_N / QBLK) * B_N), 256, 0, stream>>>(Qb, Kb, Vtb, out);
}

// Round 3
// 223.773 us; speedup vs baseline: 1.1182x; 1.1182x over previous
//
#include <hip/hip_runtime.h>
#include <hip/hip_bf16.h>

// ---------------- problem constants ----------------
#define B_N   8
#define S_N   4096
#define D_N   256          // DQK == DV
#define QBLK  64           // q rows per block (32 per wave, 2 waves)
#define KVBLK 64
#define SCALE 0.0625f      // 1/sqrt(256), folded into Q prepass

typedef __attribute__((ext_vector_type(8)))  short bf16x8;
typedef __attribute__((ext_vector_type(16))) float f32x16;

// ---------------- async global->LDS (16B/lane, wave-uniform LDS base) -------
__device__ __forceinline__ void async16(const char* g, char* l) {
  __builtin_amdgcn_global_load_lds(
      (const __attribute__((address_space(1))) void*)g,
      (__attribute__((address_space(3))) void*)l, 16, 0, 0);
}

__device__ __forceinline__ unsigned cvt_pk_bf16(float lo, float hi) {
  unsigned r;
  asm("v_cvt_pk_bf16_f32 %0, %1, %2" : "=v"(r) : "v"(lo), "v"(hi));
  return r;
}
// upper 32 lanes of a <-> lower 32 lanes of b (hardware semantics)
__device__ __forceinline__ void swap32(unsigned& a, unsigned& b) {
  asm("v_permlane32_swap_b32 %0, %1" : "+v"(a), "+v"(b));
}
// full-wave combine of per-half partials: every lane gets op(own, cross-half).
// NOTE: the opaque asm on b is essential — without it a and b are the same SSA
// value and the register allocator aliases both "+v" operands to ONE register,
// turning the swap into an in-place half-rotate (round-2 correctness bug).
__device__ __forceinline__ float xhalf_max(float x) {
  float a = x, b = x;
  asm("" : "+v"(b));                    // force b into its own register
  asm("v_permlane32_swap_b32 %0, %1" : "+v"(a), "+v"(b));
  return fmaxf(a, b);
}
__device__ __forceinline__ float xhalf_add(float x) {
  float a = x, b = x;
  asm("" : "+v"(b));
  asm("v_permlane32_swap_b32 %0, %1" : "+v"(a), "+v"(b));
  return a + b;
}

// ---------------- prepass: NCHW -> (B,S,D) bf16 with pos add (+scale) -------
__global__ void prep_qk(const float* __restrict__ src, const float* __restrict__ pos,
                        __hip_bfloat16* __restrict__ dst, float mul) {
  __shared__ float tile[64][65];
  const int b  = blockIdx.z;
  const int s0 = blockIdx.x * 64;
  const int c0 = blockIdx.y * 64;
  const int t  = threadIdx.x;
  const int x  = t & 63;
  const int y4 = t >> 6;
  const float* sp = src + ((size_t)b * D_N + c0) * S_N + s0;
#pragma unroll
  for (int i = 0; i < 16; ++i) {
    int c = y4 + i * 4;
    tile[c][x] = sp[(size_t)c * S_N + x];
  }
  __syncthreads();
  __hip_bfloat16* dp = dst + ((size_t)b * S_N + s0) * D_N + c0;
  const float* pp = pos + (size_t)s0 * D_N + c0;
#pragma unroll
  for (int i = 0; i < 16; ++i) {
    int s = y4 + i * 4;
    float v = (tile[x][s] + pp[(size_t)s * D_N + x]) * mul;
    dp[(size_t)s * D_N + x] = __float2bfloat16(v);
  }
}

// V: (B,D,S) fp32 -> (B,D,S) bf16 cast
struct alignas(8) bf4 { __hip_bfloat16 a, b, c, d; };
__global__ void prep_v(const float* __restrict__ src, __hip_bfloat16* __restrict__ dst) {
  size_t i = (size_t)blockIdx.x * blockDim.x + threadIdx.x;
  float4 v = reinterpret_cast<const float4*>(src)[i];
  bf4 o { __float2bfloat16(v.x), __float2bfloat16(v.y),
          __float2bfloat16(v.z), __float2bfloat16(v.w) };
  *reinterpret_cast<bf4*>(dst + i * 4) = o;
}

// ---------------- flash attention, 32x32 MFMA, swapped-operand form ---------
// LDS: [0,32KB) K tile (64 keys x 512B, XOR-swizzled 16B slots)
//      [32KB,64KB) Vt tile (256 d x 128B, XOR-swizzled 16B slots)
#define LDS_BYTES 65536

__global__ __launch_bounds__(128, 1) void attn_kernel(
    const __hip_bfloat16* __restrict__ Qb, const __hip_bfloat16* __restrict__ Kb,
    const __hip_bfloat16* __restrict__ Vtb, float* __restrict__ out) {
  __shared__ __align__(16) char lds[LDS_BYTES];

  const int tid  = threadIdx.x;
  const int wave = tid >> 6;
  const int lane = tid & 63;
  const int l31  = lane & 31;
  const int h    = lane >> 5;        // cross-half index
  const int l7   = lane & 7;

  // XCD swizzle: hw block i -> XCD i%8; put all of batch b on XCD b
  const int lin   = blockIdx.x;          // 0..511
  const int b     = lin & 7;
  const int qtile = lin >> 3;            // 0..63
  const int q0    = qtile * QBLK + wave * 32;

  // ---- Q fragments, resident in registers (B-operand layout) ----
  // lane (q=l31, h): qf[kc] = Q[q0+q][kc*16 + h*8 .. +7]
  bf16x8 qf[16];
  {
    const __hip_bfloat16* qp = Qb + ((size_t)b * S_N + q0 + l31) * D_N + h * 8;
#pragma unroll
    for (int kc = 0; kc < 16; ++kc)
      qf[kc] = *reinterpret_cast<const bf16x8*>(qp + kc * 16);
  }

  // ---- accumulators: O^T, C-layout col=q row=d (8 d-frags of 32) ----
  f32x16 o[8];
#pragma unroll
  for (int df = 0; df < 8; ++df)
#pragma unroll
    for (int r = 0; r < 16; ++r) o[df][r] = 0.f;
  float m_ = -1e30f, l_ = 0.f;

  char* Klds = lds;
  char* Vlds = lds + 32768;
  const char* kgbase = reinterpret_cast<const char*>(Kb  + (size_t)b * S_N * D_N);
  const char* vgbase = reinterpret_cast<const char*>(Vtb + (size_t)b * D_N * S_N);

  for (int t = 0; t < S_N / KVBLK; ++t) {
    __syncthreads();   // previous tile fully consumed
    {
      // K tile: 64 rows x 512B. Source pre-swizzled -> linear LDS holds swizzled data.
      const char* kt = kgbase + (size_t)t * KVBLK * (D_N * 2);
#pragma unroll
      for (int i = 0; i < 16; ++i) {
        int c    = wave * 16 + i;            // 32 x 1KB segments
        int T    = c * 1024 + lane * 16;
        int row  = T >> 9;
        int colb = T & 511;
        async16(kt + row * 512 + (colb ^ ((row & 7) << 4)), Klds + c * 1024);
      }
      // Vt tile: 256 d-rows x 128B (global row stride S*2 = 8192B)
      const char* vt = vgbase + (size_t)t * KVBLK * 2;
#pragma unroll
      for (int i = 0; i < 16; ++i) {
        int c    = wave * 16 + i;
        int T    = c * 1024 + lane * 16;
        int d    = T >> 7;
        int colb = T & 127;
        async16(vt + (size_t)d * (S_N * 2) + (colb ^ ((d & 7) << 4)), Vlds + c * 1024);
      }
    }
    __syncthreads();   // staged data visible (vmcnt drained before barrier)

    // ---- QK^T (swapped): S^T[key][q] = mfma(A=K, B=Q) ----
    f32x16 se[2];
#pragma unroll
    for (int e = 0; e < 2; ++e) {
#pragma unroll
      for (int r = 0; r < 16; ++r) se[e][r] = 0.f;
      const char* kr = Klds + (e * 32 + l31) * 512;
      const int swz = l7 << 4;             // key&7 == lane&7
#pragma unroll
      for (int kc = 0; kc < 16; ++kc) {
        bf16x8 kf = *reinterpret_cast<const bf16x8*>(kr + ((kc * 32 + h * 16) ^ swz));
        se[e] = __builtin_amdgcn_mfma_f32_32x32x16_bf16(kf, qf[kc], se[e], 0, 0, 0);
      }
    }

    // ---- online softmax, lane-local partials + one cross-half combine ----
    float t8[8];
#pragma unroll
    for (int i = 0; i < 8; ++i)
      t8[i] = fmaxf(fmaxf(se[0][i], se[0][i + 8]), fmaxf(se[1][i], se[1][i + 8]));
    float pm = fmaxf(fmaxf(fmaxf(t8[0], t8[1]), fmaxf(t8[2], t8[3])),
                     fmaxf(fmaxf(t8[4], t8[5]), fmaxf(t8[6], t8[7])));
    float pmax = xhalf_max(pm);            // full-row max (both halves agree)

    if (!__all(pmax <= m_ + 8.f)) {        // defer-max: rescale only on real growth
      float mn = fmaxf(m_, pmax);
      float al = __expf(m_ - mn);
      m_ = mn;
      l_ *= al;
#pragma unroll
      for (int df = 0; df < 8; ++df)
#pragma unroll
        for (int r = 0; r < 16; ++r) o[df][r] *= al;
    }
#pragma unroll
    for (int r = 0; r < 16; ++r) se[0][r] = __expf(se[0][r] - m_);
#pragma unroll
    for (int r = 0; r < 16; ++r) se[1][r] = __expf(se[1][r] - m_);
    float s8[8];
#pragma unroll
    for (int i = 0; i < 8; ++i)
      s8[i] = (se[0][i] + se[0][i + 8]) + (se[1][i] + se[1][i + 8]);
    float rs = ((s8[0] + s8[1]) + (s8[2] + s8[3])) + ((s8[4] + s8[5]) + (s8[6] + s8[7]));
    l_ += xhalf_add(rs);

    // ---- P -> bf16 B-fragments in-register (cvt_pk + permlane32_swap) ----
    // S-frag e rows: h=0 holds keys {0-3,8-11,16-19,24-27}(+32e), h=1 +4.
    // B-frag kf word w must hold keys kf*16 + h*8 + {2w,2w+1}.
    union U8 { unsigned u[4]; bf16x8 v; };
    U8 pb[4];
#pragma unroll
    for (int e = 0; e < 2; ++e) {
      unsigned u0 = cvt_pk_bf16(se[e][0],  se[e][1]);
      unsigned v0 = cvt_pk_bf16(se[e][4],  se[e][5]);
      swap32(u0, v0);                       // -> kf=2e: w0, w2
      unsigned u1 = cvt_pk_bf16(se[e][2],  se[e][3]);
      unsigned v1 = cvt_pk_bf16(se[e][6],  se[e][7]);
      swap32(u1, v1);                       // -> kf=2e: w1, w3
      pb[2 * e].u[0] = u0; pb[2 * e].u[1] = u1;
      pb[2 * e].u[2] = v0; pb[2 * e].u[3] = v1;
      unsigned u2 = cvt_pk_bf16(se[e][8],  se[e][9]);
      unsigned v2 = cvt_pk_bf16(se[e][12], se[e][13]);
      swap32(u2, v2);                       // -> kf=2e+1: w0, w2
      unsigned u3 = cvt_pk_bf16(se[e][10], se[e][11]);
      unsigned v3 = cvt_pk_bf16(se[e][14], se[e][15]);
      swap32(u3, v3);                       // -> kf=2e+1: w1, w3
      pb[2 * e + 1].u[0] = u2; pb[2 * e + 1].u[1] = u3;
      pb[2 * e + 1].u[2] = v2; pb[2 * e + 1].u[3] = v3;
    }

    // ---- PV (swapped): O^T[d][q] += mfma(A=V^T, B=P) ----
#pragma unroll
    for (int df = 0; df < 8; ++df) {
      const char* vr = Vlds + (df * 32 + l31) * 128;
      const int swz = l7 << 4;             // d&7 == lane&7
#pragma unroll
      for (int kf = 0; kf < 4; ++kf) {
        bf16x8 vf = *reinterpret_cast<const bf16x8*>(vr + ((kf * 32 + h * 16) ^ swz));
        o[df] = __builtin_amdgcn_mfma_f32_32x32x16_bf16(vf, pb[kf].v, o[df], 0, 0, 0);
      }
    }
  }

  // ---- epilogue: normalize and store O^T directly to (B,D,S) fp32 ----
  const float invl = 1.0f / l_;
  float* ob = out + (size_t)b * D_N * S_N + q0 + l31;
#pragma unroll
  for (int df = 0; df < 8; ++df)
#pragma unroll
    for (int r = 0; r < 16; ++r) {
      int d = df * 32 + (r & 3) + 8 * (r >> 2) + 4 * h;
      ob[(size_t)d * S_N] = o[df][r] * invl;
    }
}

// ---------------- launch ----------------
extern "C" void kernel_launch(void* const* d_in, const int* in_sizes, int n_in,
                              void* d_out, int out_size, void* d_ws, size_t ws_size,
                              hipStream_t stream) {
  const float* queries = (const float*)d_in[0];
  const float* keys    = (const float*)d_in[1];
  const float* values  = (const float*)d_in[2];
  const float* q_pos   = (const float*)d_in[3];
  const float* k_pos   = (const float*)d_in[4];
  float* out = (float*)d_out;

  const size_t per = (size_t)B_N * S_N * D_N;
  __hip_bfloat16* Qb  = (__hip_bfloat16*)d_ws;
  __hip_bfloat16* Kb  = Qb + per;
  __hip_bfloat16* Vtb = Kb + per;          // 50.3 MB of ws total

  prep_qk<<<dim3(S_N / 64, D_N / 64, B_N), 256, 0, stream>>>(queries, q_pos, Qb, SCALE);
  prep_qk<<<dim3(S_N / 64, D_N / 64, B_N), 256, 0, stream>>>(keys,    k_pos, Kb, 1.0f);
  prep_v <<<dim3((unsigned)(per / 4 / 256)), 256, 0, stream>>>(values, Vtb);
  attn_kernel<<<dim3((S_N / QBLK) * B_N), 128, 0, stream>>>(Qb, Kb, Vtb, out);
}